// Round 1
// baseline (42876.865 us; speedup 1.0000x reference)
//
#include <hip/hip_runtime.h>
#include <hip/hip_bf16.h>

#define B_ 16
#define S_ 256
#define E_ 512
#define H_ 1024
#define V_ 32000

typedef __attribute__((ext_vector_type(8))) short short8;
typedef __attribute__((ext_vector_type(4))) float f32x4;

__device__ __forceinline__ unsigned short f2bf(float f) {
  unsigned u = __builtin_bit_cast(unsigned, f);
  u = u + 0x7fffu + ((u >> 16) & 1u);   // round-to-nearest-even
  return (unsigned short)(u >> 16);
}

// ---------------- prep kernels ----------------

__global__ void k_init(float* __restrict__ p, int n) {
  int i = blockIdx.x * 256 + threadIdx.x;
  if (i < n) p[i] = 0.f;
}

__global__ void k_cast(const float* __restrict__ s, unsigned short* __restrict__ d, int n4) {
  int i = blockIdx.x * 256 + threadIdx.x;
  if (i >= n4) return;
  float4 v = ((const float4*)s)[i];
  ushort4 o;
  o.x = f2bf(v.x); o.y = f2bf(v.y); o.z = f2bf(v.z); o.w = f2bf(v.w);
  ((ushort4*)d)[i] = o;
}

// xe[m][k] = bf16(emb[x[b,s]][k]), m = s*16 + b
__global__ void k_gather(const int* __restrict__ x, const float* __restrict__ emb,
                         unsigned short* __restrict__ xe) {
  int m = blockIdx.x;
  int s = m >> 4, b = m & 15;
  int tok = x[b * S_ + s];
  int k = threadIdx.x * 4;
  float4 v = *(const float4*)(emb + (size_t)tok * E_ + k);
  ushort4 o;
  o.x = f2bf(v.x); o.y = f2bf(v.y); o.z = f2bf(v.z); o.w = f2bf(v.w);
  *(ushort4*)(xe + (size_t)m * E_ + k) = o;
}

// ---------------- bf16 MFMA GEMM:  C[m][n] = sum_k A[m,k]*W[n,k] + bias[n] ----------------
// A: [M][K] bf16.  W given as up to 3 gate pointers, each [1024][K] (or one big [N][K] with gshift=30).
// 128x128 tile, BK=32, 4 waves each computing 64x64 via 4x4 frags of 16x16x32.

__global__ __launch_bounds__(256, 1) void k_gemm(
    const unsigned short* __restrict__ A,
    const unsigned short* __restrict__ W0, const unsigned short* __restrict__ W1,
    const unsigned short* __restrict__ W2,
    const float* __restrict__ b0, const float* __restrict__ b1, const float* __restrict__ b2,
    float* __restrict__ C, int K, int mtiles, int gshift, int permute, int ldc) {
  __shared__ unsigned short As[128][40];  // +8 pad: 80B row stride keeps b128 reads ~2-way
  __shared__ unsigned short Bs[128][40];

  const int tid = threadIdx.x;
  const int mt = blockIdx.x % mtiles, nt = blockIdx.x / mtiles;
  const int m0 = mt * 128, n0 = nt * 128;
  const int wave = tid >> 6, lane = tid & 63;
  const int wm = (wave >> 1) * 64, wn = (wave & 1) * 64;
  const int lr = lane & 15, lk = (lane >> 4) * 8;
  const int ar = tid >> 2, as = (tid & 3) * 8;  // staging: row 0..63(+64), 8-elem slot
  const unsigned kmask = (1u << gshift) - 1u;

  int j1 = n0 + ar, j2 = n0 + ar + 64;
  int g1 = j1 >> gshift, g2 = j2 >> gshift;
  const unsigned short* bp1 = (g1 == 0 ? W0 : (g1 == 1 ? W1 : W2)) + (size_t)(j1 & kmask) * K + as;
  const unsigned short* bp2 = (g2 == 0 ? W0 : (g2 == 1 ? W1 : W2)) + (size_t)(j2 & kmask) * K + as;
  const unsigned short* ap1 = A + (size_t)(m0 + ar) * K + as;
  const unsigned short* ap2 = A + (size_t)(m0 + ar + 64) * K + as;

  const f32x4 zero4 = {0.f, 0.f, 0.f, 0.f};
  f32x4 acc[4][4];
#pragma unroll
  for (int i = 0; i < 4; ++i)
#pragma unroll
    for (int j = 0; j < 4; ++j) acc[i][j] = zero4;

  for (int k0 = 0; k0 < K; k0 += 32) {
    int4 va1 = *(const int4*)(ap1 + k0);
    int4 va2 = *(const int4*)(ap2 + k0);
    int4 vb1 = *(const int4*)(bp1 + k0);
    int4 vb2 = *(const int4*)(bp2 + k0);
    __syncthreads();
    *(int4*)&As[ar][as] = va1;
    *(int4*)&As[ar + 64][as] = va2;
    *(int4*)&Bs[ar][as] = vb1;
    *(int4*)&Bs[ar + 64][as] = vb2;
    __syncthreads();
    short8 af[4], bf[4];
#pragma unroll
    for (int i = 0; i < 4; ++i) af[i] = *(const short8*)&As[wm + i * 16 + lr][lk];
#pragma unroll
    for (int j = 0; j < 4; ++j) bf[j] = *(const short8*)&Bs[wn + j * 16 + lr][lk];
#pragma unroll
    for (int i = 0; i < 4; ++i)
#pragma unroll
      for (int j = 0; j < 4; ++j)
        acc[i][j] = __builtin_amdgcn_mfma_f32_16x16x32_bf16(af[i], bf[j], acc[i][j], 0, 0, 0);
  }

#pragma unroll
  for (int j = 0; j < 4; ++j) {
    int col = n0 + wn + j * 16 + lr;
    int g = col >> gshift;
    const float* bp = (g == 0 ? b0 : (g == 1 ? b1 : b2));
    float bv = bp[col & kmask];
#pragma unroll
    for (int i = 0; i < 4; ++i) {
      int rbase = m0 + wm + i * 16 + (lane >> 4) * 4;
#pragma unroll
      for (int r = 0; r < 4; ++r) {
        int mrow = rbase + r;
        size_t off;
        if (permute) {  // m = s*16+b  ->  out[(b*S + s)][col]
          int s = mrow >> 4, b = mrow & 15;
          off = ((size_t)(b * S_ + s)) * ldc + col;
        } else {
          off = (size_t)mrow * ldc + col;
        }
        C[off] = acc[i][j][r] + bv;
      }
    }
  }
}

// ---------------- persistent GRU scan ----------------

__device__ __forceinline__ void gbar(unsigned* bar, unsigned nb) {
  __syncthreads();
  if (threadIdx.x == 0) {
    __threadfence();
    unsigned g = __hip_atomic_load(bar + 1, __ATOMIC_RELAXED, __HIP_MEMORY_SCOPE_AGENT);
    unsigned a = __hip_atomic_fetch_add(bar, 1u, __ATOMIC_ACQ_REL, __HIP_MEMORY_SCOPE_AGENT);
    if (a == nb - 1u) {
      __hip_atomic_store(bar, 0u, __ATOMIC_RELAXED, __HIP_MEMORY_SCOPE_AGENT);
      __hip_atomic_fetch_add(bar + 1, 1u, __ATOMIC_RELEASE, __HIP_MEMORY_SCOPE_AGENT);
    } else {
      while (__hip_atomic_load(bar + 1, __ATOMIC_ACQUIRE, __HIP_MEMORY_SCOPE_AGENT) == g)
        __builtin_amdgcn_s_sleep(2);
    }
    __threadfence();
  }
  __syncthreads();
}

// 256 blocks x 256 threads, all co-resident (0 LDS, <=1 block/CU needed).
// Block owns features j0..j0+3 of each gate; all 12 weight rows live in registers.
// Wave w handles batch rows 4w..4w+3. Two device barriers per step.
__global__ __launch_bounds__(256, 1) void k_scan(
    const float* __restrict__ Gx,  // [S][B][3H]  (z|r|n)
    const float* __restrict__ Whz, const float* __restrict__ Whr, const float* __restrict__ Whn,
    float* __restrict__ h,         // [B][H] f32 state
    float* __restrict__ rh,        // [B][H] scratch: r*h broadcast
    unsigned short* __restrict__ Hseq,  // [S][B][H] bf16
    float* __restrict__ hfin,      // [B][H] f32 (d_out tail)
    unsigned* __restrict__ bar) {
  const int blk = blockIdx.x, tid = threadIdx.x;
  const int wave = tid >> 6, lane = tid & 63;
  const int j0 = blk * 4;
  const int kb = lane * 16;  // this lane's K chunk base

  float4 wz[4][4], wr[4][4], wn[4][4];
#pragma unroll
  for (int f = 0; f < 4; ++f) {
    const float4* pz = (const float4*)(Whz + (size_t)(j0 + f) * H_ + kb);
    const float4* pr = (const float4*)(Whr + (size_t)(j0 + f) * H_ + kb);
    const float4* pn = (const float4*)(Whn + (size_t)(j0 + f) * H_ + kb);
#pragma unroll
    for (int i = 0; i < 4; ++i) { wz[f][i] = pz[i]; wr[f][i] = pr[i]; wn[f][i] = pn[i]; }
  }

  const int bq = wave * 4;
  float zreg[4];  // z for (b=bq+bb, f=lane), valid on lanes 0..3

  for (int t = 0; t < S_; ++t) {
    const float* gxt = Gx + (size_t)t * (B_ * 3 * H_);

    // -------- phase A: z, r --------
#pragma unroll
    for (int bb = 0; bb < 4; ++bb) {
      const int b = bq + bb;
      const float4* hp = (const float4*)(h + b * H_ + kb);
      float4 h4[4];
#pragma unroll
      for (int i = 0; i < 4; ++i) h4[i] = hp[i];
      float dz[4], dr[4];
#pragma unroll
      for (int f = 0; f < 4; ++f) {
        float az = 0.f, arr = 0.f;
#pragma unroll
        for (int i = 0; i < 4; ++i) {
          az += wz[f][i].x * h4[i].x + wz[f][i].y * h4[i].y + wz[f][i].z * h4[i].z + wz[f][i].w * h4[i].w;
          arr += wr[f][i].x * h4[i].x + wr[f][i].y * h4[i].y + wr[f][i].z * h4[i].z + wr[f][i].w * h4[i].w;
        }
        dz[f] = az; dr[f] = arr;
      }
#pragma unroll
      for (int f = 0; f < 4; ++f) {
#pragma unroll
        for (int off = 32; off; off >>= 1) {
          dz[f] += __shfl_xor(dz[f], off);
          dr[f] += __shfl_xor(dr[f], off);
        }
      }
      if (lane < 8) {
        const int f = lane & 3;
        const bool isr = lane >= 4;
        float d = isr ? ((f == 0) ? dr[0] : (f == 1) ? dr[1] : (f == 2) ? dr[2] : dr[3])
                      : ((f == 0) ? dz[0] : (f == 1) ? dz[1] : (f == 2) ? dz[2] : dz[3]);
        float gx = gxt[b * 3 * H_ + (isr ? H_ : 0) + j0 + f];
        float v = 1.f / (1.f + __expf(-(gx + d)));
        if (!isr) zreg[bb] = v;
        else rh[b * H_ + j0 + f] = v * h[b * H_ + j0 + f];
      }
    }
    gbar(bar, gridDim.x);

    // -------- phase B: n, h update --------
#pragma unroll
    for (int bb = 0; bb < 4; ++bb) {
      const int b = bq + bb;
      const float4* rp = (const float4*)(rh + b * H_ + kb);
      float4 r4[4];
#pragma unroll
      for (int i = 0; i < 4; ++i) r4[i] = rp[i];
      float dn[4];
#pragma unroll
      for (int f = 0; f < 4; ++f) {
        float an = 0.f;
#pragma unroll
        for (int i = 0; i < 4; ++i)
          an += wn[f][i].x * r4[i].x + wn[f][i].y * r4[i].y + wn[f][i].z * r4[i].z + wn[f][i].w * r4[i].w;
        dn[f] = an;
      }
#pragma unroll
      for (int f = 0; f < 4; ++f) {
#pragma unroll
        for (int off = 32; off; off >>= 1) dn[f] += __shfl_xor(dn[f], off);
      }
      if (lane < 4) {
        const int f = lane;
        float d = (f == 0) ? dn[0] : (f == 1) ? dn[1] : (f == 2) ? dn[2] : dn[3];
        float gx = gxt[b * 3 * H_ + 2 * H_ + j0 + f];
        float n = tanhf(gx + d);
        float z = zreg[bb];
        const int j = j0 + f;
        float ho = h[b * H_ + j];
        float hn = (1.f - z) * n + z * ho;
        h[b * H_ + j] = hn;
        Hseq[(size_t)t * (B_ * H_) + b * H_ + j] = f2bf(hn);
        if (t == S_ - 1) hfin[b * H_ + j] = hn;
      }
    }
    gbar(bar, gridDim.x);
  }
}

// ---------------- host ----------------

extern "C" void kernel_launch(void* const* d_in, const int* in_sizes, int n_in,
                              void* d_out, int out_size, void* d_ws, size_t ws_size,
                              hipStream_t stream) {
  const int*   x    = (const int*)d_in[0];
  const float* emb  = (const float*)d_in[1];
  const float* wxz0 = (const float*)d_in[2];
  const float* bxz0 = (const float*)d_in[3];
  const float* whz0 = (const float*)d_in[4];
  const float* wxr0 = (const float*)d_in[5];
  const float* bxr0 = (const float*)d_in[6];
  const float* whr0 = (const float*)d_in[7];
  const float* wxn0 = (const float*)d_in[8];
  const float* bxn0 = (const float*)d_in[9];
  const float* whn0 = (const float*)d_in[10];
  const float* wxz1 = (const float*)d_in[11];
  const float* bxz1 = (const float*)d_in[12];
  const float* whz1 = (const float*)d_in[13];
  const float* wxr1 = (const float*)d_in[14];
  const float* bxr1 = (const float*)d_in[15];
  const float* whr1 = (const float*)d_in[16];
  const float* wxn1 = (const float*)d_in[17];
  const float* bxn1 = (const float*)d_in[18];
  const float* whn1 = (const float*)d_in[19];
  const float* fcw  = (const float*)d_in[20];
  const float* fcb  = (const float*)d_in[21];
  float* out = (float*)d_out;

  char* w = (char*)d_ws;
  size_t off = 0;
  auto alloc = [&](size_t bytes) {
    void* p = w + off;
    off += (bytes + 255) & ~(size_t)255;
    return p;
  };
  unsigned short* xe   = (unsigned short*)alloc((size_t)4096 * E_ * 2);
  unsigned short* wz0b = (unsigned short*)alloc((size_t)H_ * E_ * 2);
  unsigned short* wr0b = (unsigned short*)alloc((size_t)H_ * E_ * 2);
  unsigned short* wn0b = (unsigned short*)alloc((size_t)H_ * E_ * 2);
  unsigned short* wz1b = (unsigned short*)alloc((size_t)H_ * H_ * 2);
  unsigned short* wr1b = (unsigned short*)alloc((size_t)H_ * H_ * 2);
  unsigned short* wn1b = (unsigned short*)alloc((size_t)H_ * H_ * 2);
  unsigned short* fcwb = (unsigned short*)alloc((size_t)V_ * H_ * 2);
  float* Gx = (float*)alloc((size_t)4096 * 3 * H_ * 4);
  unsigned short* Hs0 = (unsigned short*)alloc((size_t)4096 * H_ * 2);
  unsigned short* Hs1 = (unsigned short*)alloc((size_t)4096 * H_ * 2);
  float* h0c = (float*)alloc((size_t)B_ * H_ * 4);
  float* h1c = (float*)alloc((size_t)B_ * H_ * 4);
  float* rh  = (float*)alloc((size_t)B_ * H_ * 4);
  unsigned* bar = (unsigned*)alloc(256);

  float* h0f = out + (size_t)B_ * S_ * V_;
  float* h1f = h0f + (size_t)B_ * H_;

  // zero h0c,h1c,rh,bar (contiguous)
  int nz = B_ * H_ * 3 + 64;
  k_init<<<(nz + 255) / 256, 256, 0, stream>>>(h0c, nz);

  // prep: gather + casts
  k_gather<<<4096, 128, 0, stream>>>(x, emb, xe);
  k_cast<<<(H_ * E_ / 4 + 255) / 256, 256, 0, stream>>>(wxz0, wz0b, H_ * E_ / 4);
  k_cast<<<(H_ * E_ / 4 + 255) / 256, 256, 0, stream>>>(wxr0, wr0b, H_ * E_ / 4);
  k_cast<<<(H_ * E_ / 4 + 255) / 256, 256, 0, stream>>>(wxn0, wn0b, H_ * E_ / 4);
  k_cast<<<(H_ * H_ / 4 + 255) / 256, 256, 0, stream>>>(wxz1, wz1b, H_ * H_ / 4);
  k_cast<<<(H_ * H_ / 4 + 255) / 256, 256, 0, stream>>>(wxr1, wr1b, H_ * H_ / 4);
  k_cast<<<(H_ * H_ / 4 + 255) / 256, 256, 0, stream>>>(wxn1, wn1b, H_ * H_ / 4);
  k_cast<<<(V_ * H_ / 4 + 255) / 256, 256, 0, stream>>>(fcw, fcwb, V_ * H_ / 4);

  // Gx0 = xe @ Wx0^T + b  (M=4096, N=3072, K=512)
  k_gemm<<<32 * 24, 256, 0, stream>>>(xe, wz0b, wr0b, wn0b, bxz0, bxr0, bxn0,
                                      Gx, E_, 32, 10, 0, 3 * H_);
  // layer-0 scan
  k_scan<<<256, 256, 0, stream>>>(Gx, whz0, whr0, whn0, h0c, rh, Hs0, h0f, bar);
  // Gx1 = H0seq @ Wx1^T + b  (K=1024)
  k_gemm<<<32 * 24, 256, 0, stream>>>(Hs0, wz1b, wr1b, wn1b, bxz1, bxr1, bxn1,
                                      Gx, H_, 32, 10, 0, 3 * H_);
  // layer-1 scan
  k_scan<<<256, 256, 0, stream>>>(Gx, whz1, whr1, whn1, h1c, rh, Hs1, h1f, bar);
  // out = H1seq @ fcw^T + fcb  (M=4096, N=32000, K=1024), permuted to [B][S][V]
  k_gemm<<<32 * 250, 256, 0, stream>>>(Hs1, fcwb, fcwb, fcwb, fcb, fcb, fcb,
                                       out, H_, 32, 30, 1, V_);

  (void)in_sizes; (void)n_in; (void)out_size; (void)ws_size;
}